// Round 12
// baseline (942.508 us; speedup 1.0000x reference)
//
#include <hip/hip_runtime.h>

#define HW 65536
#define W_IMG 256
#define H_IMG 256
#define CIN 64
#define CHID 384
#define CQK 128

// ---------------- K1: 1x1 expansion GEMM (LDS-free, 3-buffer pipeline) ----------------
// block = 48co x 256px, 4 waves; wave owns 12co x 256px; lane owns 12co x 4px.
// 3-buffer rotation: 2 chunks (~768 FMA-cycles) in flight covers L3 latency.
#define K1_LOAD(B, CHUNK) { \
    _Pragma("unroll") for (int u = 0; u < 4; ++u) \
        B[u] = *reinterpret_cast<const float4*>(&x[(size_t)((CHUNK) * 4 + u) * HW + px]); }
#define K1_COMP(B, CHUNK) { \
    _Pragma("unroll") for (int i = 0; i < 12; ++i) { \
        float4 wv = *reinterpret_cast<const float4*>(&wh[(size_t)(cw + i) * CIN + (CHUNK) * 4]); \
        float wu[4] = {wv.x, wv.y, wv.z, wv.w}; \
        _Pragma("unroll") for (int u = 0; u < 4; ++u) { \
            acc[i][0] += wu[u] * B[u].x; \
            acc[i][1] += wu[u] * B[u].y; \
            acc[i][2] += wu[u] * B[u].z; \
            acc[i][3] += wu[u] * B[u].w; } } }

__global__ __launch_bounds__(256) void k1_expand(
    const float* __restrict__ x_base,    // [B][CIN][HW]
    const float* __restrict__ wh,        // [CHID][CIN]
    const float* __restrict__ bh,        // [CHID]
    float* __restrict__ hidden_base,     // [B][CHID][HW]
    size_t x_bstride, size_t hid_bstride)
{
    const float* x = x_base + blockIdx.z * x_bstride;
    float* hidden  = hidden_base + blockIdx.z * hid_bstride;
    const int pxbase = blockIdx.x * 256;
    const int cobase = blockIdx.y * 48;
    const int tid  = threadIdx.x;
    const int lane = tid & 63;
    const int wq   = __builtin_amdgcn_readfirstlane(tid >> 6);
    const int px   = pxbase + lane * 4;
    const int cw   = cobase + wq * 12;    // wave-uniform

    float acc[12][4];
    #pragma unroll
    for (int i = 0; i < 12; ++i)
        #pragma unroll
        for (int j = 0; j < 4; ++j) acc[i][j] = 0.f;

    float4 b0[4], b1[4], b2[4];
    K1_LOAD(b0, 0)
    K1_LOAD(b1, 1)

    #pragma unroll
    for (int t = 0; t < 16; ++t) {
        if (t + 2 < 16) {
            if (((t + 2) % 3) == 0)      { K1_LOAD(b0, t + 2) }
            else if (((t + 2) % 3) == 1) { K1_LOAD(b1, t + 2) }
            else                         { K1_LOAD(b2, t + 2) }
        }
        if ((t % 3) == 0)      { K1_COMP(b0, t) }
        else if ((t % 3) == 1) { K1_COMP(b1, t) }
        else                   { K1_COMP(b2, t) }
    }

    #pragma unroll
    for (int i = 0; i < 12; ++i) {
        int co = cw + i;
        float b = bh[co];
        float4 o;
        o.x = acc[i][0] + b; o.y = acc[i][1] + b;
        o.z = acc[i][2] + b; o.w = acc[i][3] + b;
        *reinterpret_cast<float4*>(&hidden[(size_t)co * HW + px]) = o;
    }
}

// ---------------- K2: fused depthwise 3x3 + 8x8 circular conv + v-mul ----------------
// v9: block = (channel, 32-row strip). Conv thread owns HALF a patch (4 out rows):
// q-patch resident in regs, k streamed -> 64 B LDS-read per output (was 256 B).
// `half` is wave-uniform (tid>>7); template<I0> keeps register indices static.
#define K2ROWS 32
#define K2_CH  8704    // 32*272 floats
#define K2_ROW 272     // 4 segs x 68

template<int I0>
__device__ __forceinline__ void conv_half(
    const float* __restrict__ qb, const float* __restrict__ kb, float acc[4][8])
{
    float qv[64];
    #pragma unroll
    for (int m = 0; m < 16; ++m) {
        float4 t = *reinterpret_cast<const float4*>(&qb[m * 4]);
        qv[m * 4]     = t.x;
        qv[m * 4 + 1] = t.y;
        qv[m * 4 + 2] = t.z;
        qv[m * 4 + 3] = t.w;
    }
    #pragma unroll
    for (int s = 0; s < 8; ++s) {
        float4 ka = *reinterpret_cast<const float4*>(&kb[s * 8]);
        float4 kc = *reinterpret_cast<const float4*>(&kb[s * 8 + 4]);
        float kr[8] = {ka.x, ka.y, ka.z, ka.w, kc.x, kc.y, kc.z, kc.w};
        #pragma unroll
        for (int ii = 0; ii < 4; ++ii) {
            const int qr = (I0 + ii - s) & 7;   // compile-time
            #pragma unroll
            for (int t = 0; t < 8; ++t)
                #pragma unroll
                for (int j = 0; j < 8; ++j)
                    acc[ii][j] += kr[t] * qv[qr * 8 + ((j - t) & 7)];
        }
    }
}

__global__ __launch_bounds__(256) void k2_fused(
    const float* __restrict__ hidden_base,  // [B][CHID][HW]
    const float* __restrict__ wdw,          // [CHID][9]
    const float* __restrict__ bdw,          // [CHID]
    float* __restrict__ vout_base,          // [B][CQK][HW]
    size_t hid_bstride, size_t vout_bstride)
{
    __shared__ float qk[2 * K2_CH];      // 69.6 KB: dw q,k for 32 rows

    const float* hidden = hidden_base + blockIdx.z * hid_bstride;
    float* vout         = vout_base + blockIdx.z * vout_bstride;

    const int c  = blockIdx.y;
    const int r0 = blockIdx.x * K2ROWS;
    const int tid = threadIdx.x;

    // ---- phase 1: depthwise q,k for 32 rows (4 passes of 8 rows), global-direct + shfl edges
    {
        const int rowb  = tid >> 5;      // 0..7
        const int col32 = tid & 31;
        const int px8   = col32 * 8;
        const float* wq9 = wdw + c * 9;
        const float* wk9 = wdw + (c + CQK) * 9;
        const float qb9 = bdw[c];
        const float kb9 = bdw[c + CQK];

        #pragma unroll
        for (int rp = 0; rp < 4; ++rp) {
            const int row_local = rp * 8 + rowb;
            const int gro = r0 + row_local;

            float4 qa0[3], qa1[3], ka0[3], ka1[3];
            #pragma unroll
            for (int ky = 0; ky < 3; ++ky) {
                int grr = gro + ky - 1;
                qa0[ky] = make_float4(0.f,0.f,0.f,0.f); qa1[ky] = qa0[ky];
                ka0[ky] = qa0[ky];                      ka1[ky] = qa0[ky];
                if ((unsigned)grr < H_IMG) {
                    const float* rq = hidden + (size_t)c * HW + (size_t)grr * W_IMG;
                    const float* rk = hidden + (size_t)(c + CQK) * HW + (size_t)grr * W_IMG;
                    qa0[ky] = *reinterpret_cast<const float4*>(&rq[px8]);
                    qa1[ky] = *reinterpret_cast<const float4*>(&rq[px8 + 4]);
                    ka0[ky] = *reinterpret_cast<const float4*>(&rk[px8]);
                    ka1[ky] = *reinterpret_cast<const float4*>(&rk[px8 + 4]);
                }
            }
            #pragma unroll
            for (int ch = 0; ch < 2; ++ch) {
                const float4* a0 = ch ? ka0 : qa0;
                const float4* a1 = ch ? ka1 : qa1;
                const float* wv = ch ? wk9 : wq9;
                float accd[8];
                #pragma unroll
                for (int j = 0; j < 8; ++j) accd[j] = ch ? kb9 : qb9;
                #pragma unroll
                for (int ky = 0; ky < 3; ++ky) {
                    float kw0 = wv[ky * 3], kw1 = wv[ky * 3 + 1], kw2 = wv[ky * 3 + 2];
                    float lf = __shfl_up(a1[ky].w, 1);
                    float rt = __shfl_down(a0[ky].x, 1);
                    if (col32 == 0)  lf = 0.f;
                    if (col32 == 31) rt = 0.f;
                    float h[10] = {lf, a0[ky].x, a0[ky].y, a0[ky].z, a0[ky].w,
                                       a1[ky].x, a1[ky].y, a1[ky].z, a1[ky].w, rt};
                    #pragma unroll
                    for (int j = 0; j < 8; ++j)
                        accd[j] += h[j] * kw0 + h[j + 1] * kw1 + h[j + 2] * kw2;
                }
                float* dst = &qk[ch * K2_CH + row_local * K2_ROW
                                 + (px8 >> 6) * 68 + (px8 & 63)];
                float4 o0, o1;
                o0.x = accd[0]; o0.y = accd[1]; o0.z = accd[2]; o0.w = accd[3];
                o1.x = accd[4]; o1.y = accd[5]; o1.z = accd[6]; o1.w = accd[7];
                *reinterpret_cast<float4*>(dst)     = o0;
                *reinterpret_cast<float4*>(dst + 4) = o1;
            }
        }
    }

    // ---- conv-phase mapping (half is wave-uniform)
    const int half = __builtin_amdgcn_readfirstlane(tid >> 7);   // 0/1
    const int p    = tid & 127;         // patch id
    const int prow = p >> 2;            // 0..31
    const int seg  = p & 3;
    const int gr   = r0 + prow;
    const int wp0  = seg * 64 + half * 32;   // 32 output cols

    // ---- issue v loads before the barrier (latency spans it)
    const float* rbv = hidden + (size_t)(c + 2 * CQK) * HW;
    float4 hv[3][8];
    float  hm[3], hp[3];
    #pragma unroll
    for (int ky = 0; ky < 3; ++ky) {
        int grr = gr + ky - 1;
        #pragma unroll
        for (int u = 0; u < 8; ++u) hv[ky][u] = make_float4(0.f,0.f,0.f,0.f);
        hm[ky] = 0.f; hp[ky] = 0.f;
        if ((unsigned)grr < H_IMG) {
            const float* rb = rbv + (size_t)grr * W_IMG;
            #pragma unroll
            for (int u = 0; u < 8; ++u)
                hv[ky][u] = *reinterpret_cast<const float4*>(&rb[wp0 + u * 4]);
            hm[ky] = (wp0 > 0)        ? rb[wp0 - 1]  : 0.f;
            hp[ky] = (wp0 + 32 < 256) ? rb[wp0 + 32] : 0.f;
        }
    }

    __syncthreads();

    // ---- v depthwise first (frees the 102 load regs before conv needs 96)
    const float* wvv = wdw + (c + 2 * CQK) * 9;
    const float vbias = bdw[c + 2 * CQK];
    float vc[32];
    #pragma unroll
    for (int m = 0; m < 32; ++m) vc[m] = vbias;
    #pragma unroll
    for (int ky = 0; ky < 3; ++ky) {
        float kw0 = wvv[ky * 3], kw1 = wvv[ky * 3 + 1], kw2 = wvv[ky * 3 + 2];
        float h[34];
        h[0] = hm[ky];
        #pragma unroll
        for (int u = 0; u < 8; ++u) {
            h[1 + u * 4] = hv[ky][u].x; h[2 + u * 4] = hv[ky][u].y;
            h[3 + u * 4] = hv[ky][u].z; h[4 + u * 4] = hv[ky][u].w;
        }
        h[33] = hp[ky];
        #pragma unroll
        for (int m = 0; m < 32; ++m)
            vc[m] += h[m] * kw0 + h[m + 1] * kw1 + h[m + 2] * kw2;
    }

    // ---- 8x8 circular conv, 4 output rows per thread
    const float* qb = &qk[prow * K2_ROW + seg * 68];
    const float* kb = qb + K2_CH;

    float acc[4][8];
    #pragma unroll
    for (int ii = 0; ii < 4; ++ii)
        #pragma unroll
        for (int j = 0; j < 8; ++j) acc[ii][j] = 0.f;

    if (half == 0) conv_half<0>(qb, kb, acc);
    else           conv_half<4>(qb, kb, acc);

    // ---- multiply and store 32 px
    float* dst = &vout[(size_t)c * HW + (size_t)gr * W_IMG + wp0];
    #pragma unroll
    for (int ii = 0; ii < 4; ++ii) {
        float4 o0, o1;
        o0.x = acc[ii][0] * vc[ii * 8];     o0.y = acc[ii][1] * vc[ii * 8 + 1];
        o0.z = acc[ii][2] * vc[ii * 8 + 2]; o0.w = acc[ii][3] * vc[ii * 8 + 3];
        o1.x = acc[ii][4] * vc[ii * 8 + 4]; o1.y = acc[ii][5] * vc[ii * 8 + 5];
        o1.z = acc[ii][6] * vc[ii * 8 + 6]; o1.w = acc[ii][7] * vc[ii * 8 + 7];
        *reinterpret_cast<float4*>(dst + ii * 8)     = o0;
        *reinterpret_cast<float4*>(dst + ii * 8 + 4) = o1;
    }
}

// ---------------- K3: 1x1 projection GEMM (LDS-free, ping-pong prefetch) ----------------
__global__ __launch_bounds__(256) void k3_project(
    const float* __restrict__ vout_base,  // [B][CQK][HW]
    const float* __restrict__ wo,         // [64][CQK]
    const float* __restrict__ bo,         // [64]
    float* __restrict__ out_base,         // [B][64][HW]
    size_t vout_bstride, size_t out_bstride)
{
    const float* vout = vout_base + blockIdx.z * vout_bstride;
    float* out        = out_base + blockIdx.z * out_bstride;
    const int pxbase = blockIdx.x * 256;
    const int cobase = blockIdx.y * 16;
    const int tid  = threadIdx.x;
    const int lane = tid & 63;
    const int wq   = __builtin_amdgcn_readfirstlane(tid >> 6);
    const int px   = pxbase + lane * 4;
    const int cw   = cobase + wq * 4;     // wave-uniform

    float acc[4][4];
    #pragma unroll
    for (int i = 0; i < 4; ++i)
        #pragma unroll
        for (int j = 0; j < 4; ++j) acc[i][j] = 0.f;

    float4 xa[4], xb[4];
    #pragma unroll
    for (int u = 0; u < 4; ++u)
        xa[u] = *reinterpret_cast<const float4*>(&vout[(size_t)u * HW + px]);

    #pragma unroll 1
    for (int cc4 = 0; cc4 < CQK; cc4 += 8) {
        #pragma unroll
        for (int u = 0; u < 4; ++u)
            xb[u] = *reinterpret_cast<const float4*>(&vout[(size_t)(cc4 + 4 + u) * HW + px]);
        #pragma unroll
        for (int i = 0; i < 4; ++i) {
            float4 wv = *reinterpret_cast<const float4*>(
                &wo[(size_t)(cw + i) * CQK + cc4]);   // uniform -> s_load
            float wu[4] = {wv.x, wv.y, wv.z, wv.w};
            #pragma unroll
            for (int u = 0; u < 4; ++u) {
                acc[i][0] += wu[u] * xa[u].x;
                acc[i][1] += wu[u] * xa[u].y;
                acc[i][2] += wu[u] * xa[u].z;
                acc[i][3] += wu[u] * xa[u].w;
            }
        }
        if (cc4 + 8 < CQK) {
            #pragma unroll
            for (int u = 0; u < 4; ++u)
                xa[u] = *reinterpret_cast<const float4*>(&vout[(size_t)(cc4 + 8 + u) * HW + px]);
        }
        #pragma unroll
        for (int i = 0; i < 4; ++i) {
            float4 wv = *reinterpret_cast<const float4*>(
                &wo[(size_t)(cw + i) * CQK + cc4 + 4]);
            float wu[4] = {wv.x, wv.y, wv.z, wv.w};
            #pragma unroll
            for (int u = 0; u < 4; ++u) {
                acc[i][0] += wu[u] * xb[u].x;
                acc[i][1] += wu[u] * xb[u].y;
                acc[i][2] += wu[u] * xb[u].z;
                acc[i][3] += wu[u] * xb[u].w;
            }
        }
    }

    #pragma unroll
    for (int i = 0; i < 4; ++i) {
        int co = cw + i;
        float b = bo[co];
        float4 o;
        o.x = acc[i][0] + b; o.y = acc[i][1] + b;
        o.z = acc[i][2] + b; o.w = acc[i][3] + b;
        *reinterpret_cast<float4*>(&out[(size_t)co * HW + px]) = o;
    }
}

extern "C" void kernel_launch(void* const* d_in, const int* in_sizes, int n_in,
                              void* d_out, int out_size, void* d_ws, size_t ws_size,
                              hipStream_t stream) {
    const float* x   = (const float*)d_in[0];
    const float* wh  = (const float*)d_in[1];
    const float* bh  = (const float*)d_in[2];
    const float* wdw = (const float*)d_in[3];
    const float* bdw = (const float*)d_in[4];
    const float* wo  = (const float*)d_in[5];
    const float* bo  = (const float*)d_in[6];
    float* out = (float*)d_out;

    const size_t n_hid  = (size_t)CHID * HW;
    const size_t n_vout = (size_t)CQK * HW;
    const size_t n_x    = (size_t)CIN * HW;

    if (ws_size >= 4 * (n_hid + n_vout) * sizeof(float)) {
        float* hidden = (float*)d_ws;
        float* vout   = hidden + 4 * n_hid;
        k1_expand <<<dim3(HW / 256, CHID / 48, 4),    256, 0, stream>>>(
            x, wh, bh, hidden, n_x, n_hid);
        k2_fused  <<<dim3(H_IMG / K2ROWS, CQK, 4),    256, 0, stream>>>(
            hidden, wdw, bdw, vout, n_hid, n_vout);
        k3_project<<<dim3(HW / 256, 64 / 16, 4),      256, 0, stream>>>(
            vout, wo, bo, out, n_vout, n_x);
    } else {
        float* hidden = (float*)d_ws;
        float* vout   = hidden + n_hid;
        for (int b = 0; b < 4; ++b) {
            const float* xb = x + (size_t)b * n_x;
            float* ob       = out + (size_t)b * n_x;
            k1_expand <<<dim3(HW / 256, CHID / 48, 1), 256, 0, stream>>>(
                xb, wh, bh, hidden, 0, 0);
            k2_fused  <<<dim3(H_IMG / K2ROWS, CQK, 1), 256, 0, stream>>>(
                hidden, wdw, bdw, vout, 0, 0);
            k3_project<<<dim3(HW / 256, 64 / 16, 1),   256, 0, stream>>>(
                vout, wo, bo, ob, 0, 0);
        }
    }
}

// Round 13
// 409.078 us; speedup vs baseline: 2.3040x; 2.3040x over previous
//
#include <hip/hip_runtime.h>

#define HW 65536
#define W_IMG 256
#define H_IMG 256
#define CIN 64
#define CHID 384
#define CQK 128

// ---------------- K1 body: 1x1 expansion GEMM (LDS-free, ping-pong prefetch) ----------------
// 48co x 256px per block, 4 waves; wave owns 12co; lane owns 12co x 4px. VGPR ~52.
__device__ __forceinline__ void k1_body(
    const float* __restrict__ x, const float* __restrict__ wh,
    const float* __restrict__ bh, float* __restrict__ hidden,
    int pxbase, int cobase, int tid)
{
    const int lane = tid & 63;
    const int wq   = __builtin_amdgcn_readfirstlane(tid >> 6);
    const int px   = pxbase + lane * 4;
    const int cw   = cobase + wq * 12;    // wave-uniform

    float acc[12][4];
    #pragma unroll
    for (int i = 0; i < 12; ++i)
        #pragma unroll
        for (int j = 0; j < 4; ++j) acc[i][j] = 0.f;

    float4 xa[4], xb[4];
    #pragma unroll
    for (int u = 0; u < 4; ++u)
        xa[u] = *reinterpret_cast<const float4*>(&x[(size_t)u * HW + px]);

    #pragma unroll 1
    for (int ci4 = 0; ci4 < CIN; ci4 += 8) {
        #pragma unroll
        for (int u = 0; u < 4; ++u)
            xb[u] = *reinterpret_cast<const float4*>(&x[(size_t)(ci4 + 4 + u) * HW + px]);
        #pragma unroll
        for (int i = 0; i < 12; ++i) {
            float4 wv = *reinterpret_cast<const float4*>(
                &wh[(size_t)(cw + i) * CIN + ci4]);        // wave-uniform -> s_load
            float wu[4] = {wv.x, wv.y, wv.z, wv.w};
            #pragma unroll
            for (int u = 0; u < 4; ++u) {
                acc[i][0] += wu[u] * xa[u].x;
                acc[i][1] += wu[u] * xa[u].y;
                acc[i][2] += wu[u] * xa[u].z;
                acc[i][3] += wu[u] * xa[u].w;
            }
        }
        if (ci4 + 8 < CIN) {
            #pragma unroll
            for (int u = 0; u < 4; ++u)
                xa[u] = *reinterpret_cast<const float4*>(&x[(size_t)(ci4 + 8 + u) * HW + px]);
        }
        #pragma unroll
        for (int i = 0; i < 12; ++i) {
            float4 wv = *reinterpret_cast<const float4*>(
                &wh[(size_t)(cw + i) * CIN + ci4 + 4]);
            float wu[4] = {wv.x, wv.y, wv.z, wv.w};
            #pragma unroll
            for (int u = 0; u < 4; ++u) {
                acc[i][0] += wu[u] * xb[u].x;
                acc[i][1] += wu[u] * xb[u].y;
                acc[i][2] += wu[u] * xb[u].z;
                acc[i][3] += wu[u] * xb[u].w;
            }
        }
    }

    #pragma unroll
    for (int i = 0; i < 12; ++i) {
        int co = cw + i;
        float b = bh[co];
        float4 o;
        o.x = acc[i][0] + b; o.y = acc[i][1] + b;
        o.z = acc[i][2] + b; o.w = acc[i][3] + b;
        *reinterpret_cast<float4*>(&hidden[(size_t)co * HW + px]) = o;
    }
}

// ---------------- K3 body: 1x1 projection GEMM (LDS-free, ping-pong prefetch) ----------------
// 16co x 256px per block, 4 waves; wave owns 4co x 256px.
__device__ __forceinline__ void k3_body(
    const float* __restrict__ vout, const float* __restrict__ wo,
    const float* __restrict__ bo, float* __restrict__ out,
    int pxbase, int cobase, int tid)
{
    const int lane = tid & 63;
    const int wq   = __builtin_amdgcn_readfirstlane(tid >> 6);
    const int px   = pxbase + lane * 4;
    const int cw   = cobase + wq * 4;     // wave-uniform

    float acc[4][4];
    #pragma unroll
    for (int i = 0; i < 4; ++i)
        #pragma unroll
        for (int j = 0; j < 4; ++j) acc[i][j] = 0.f;

    float4 xa[4], xb[4];
    #pragma unroll
    for (int u = 0; u < 4; ++u)
        xa[u] = *reinterpret_cast<const float4*>(&vout[(size_t)u * HW + px]);

    #pragma unroll 1
    for (int cc4 = 0; cc4 < CQK; cc4 += 8) {
        #pragma unroll
        for (int u = 0; u < 4; ++u)
            xb[u] = *reinterpret_cast<const float4*>(&vout[(size_t)(cc4 + 4 + u) * HW + px]);
        #pragma unroll
        for (int i = 0; i < 4; ++i) {
            float4 wv = *reinterpret_cast<const float4*>(
                &wo[(size_t)(cw + i) * CQK + cc4]);   // uniform -> s_load
            float wu[4] = {wv.x, wv.y, wv.z, wv.w};
            #pragma unroll
            for (int u = 0; u < 4; ++u) {
                acc[i][0] += wu[u] * xa[u].x;
                acc[i][1] += wu[u] * xa[u].y;
                acc[i][2] += wu[u] * xa[u].z;
                acc[i][3] += wu[u] * xa[u].w;
            }
        }
        if (cc4 + 8 < CQK) {
            #pragma unroll
            for (int u = 0; u < 4; ++u)
                xa[u] = *reinterpret_cast<const float4*>(&vout[(size_t)(cc4 + 8 + u) * HW + px]);
        }
        #pragma unroll
        for (int i = 0; i < 4; ++i) {
            float4 wv = *reinterpret_cast<const float4*>(
                &wo[(size_t)(cw + i) * CQK + cc4 + 4]);
            float wu[4] = {wv.x, wv.y, wv.z, wv.w};
            #pragma unroll
            for (int u = 0; u < 4; ++u) {
                acc[i][0] += wu[u] * xb[u].x;
                acc[i][1] += wu[u] * xb[u].y;
                acc[i][2] += wu[u] * xb[u].z;
                acc[i][3] += wu[u] * xb[u].w;
            }
        }
    }

    #pragma unroll
    for (int i = 0; i < 4; ++i) {
        int co = cw + i;
        float b = bo[co];
        float4 o;
        o.x = acc[i][0] + b; o.y = acc[i][1] + b;
        o.z = acc[i][2] + b; o.w = acc[i][3] + b;
        *reinterpret_cast<float4*>(&out[(size_t)co * HW + px]) = o;
    }
}

// ---------------- standalone wrappers ----------------
__global__ __launch_bounds__(256) void k1_expand(
    const float* __restrict__ x_base, const float* __restrict__ wh,
    const float* __restrict__ bh, float* __restrict__ hidden_base,
    size_t x_bstride, size_t hid_bstride)
{
    k1_body(x_base + blockIdx.z * x_bstride, wh, bh,
            hidden_base + blockIdx.z * hid_bstride,
            blockIdx.x * 256, blockIdx.y * 48, threadIdx.x);
}

__global__ __launch_bounds__(256) void k3_project(
    const float* __restrict__ vout_base, const float* __restrict__ wo,
    const float* __restrict__ bo, float* __restrict__ out_base,
    size_t vout_bstride, size_t out_bstride)
{
    k3_body(vout_base + blockIdx.z * vout_bstride, wo, bo,
            out_base + blockIdx.z * out_bstride,
            blockIdx.x * 256, blockIdx.y * 16, threadIdx.x);
}

// ---------------- merged: k3(batch b) + k1(batch b+1) in one dispatch ----------------
// y in [0,8): k1 co-block y*48 on x_next -> hidden (already consumed by k2(b)).
// y in [8,12): k3 co-block (y-8)*16 on vout(b) -> out(b). No data hazard.
__global__ __launch_bounds__(256) void k31_merged(
    const float* __restrict__ x_next, const float* __restrict__ wh,
    const float* __restrict__ bh, float* __restrict__ hidden,
    const float* __restrict__ vout, const float* __restrict__ wo,
    const float* __restrict__ bo, float* __restrict__ out_b)
{
    if (blockIdx.y < 8)
        k1_body(x_next, wh, bh, hidden, blockIdx.x * 256, blockIdx.y * 48, threadIdx.x);
    else
        k3_body(vout, wo, bo, out_b, blockIdx.x * 256, (blockIdx.y - 8) * 16, threadIdx.x);
}

// ---------------- K2: fused depthwise 3x3 + 8x8 circular conv + v-mul (v7) ----------------
// dual staging buffers (q,k loads all in flight together), ONE barrier before
// depthwise, one before phase 2; v loads stay in flight across barriers.
#define QK_CH   2208   // 8*276 floats
#define QK_ROW  276
#define QK_SEG  68
__global__ __launch_bounds__(256) void k2_fused(
    const float* __restrict__ hidden_base,  // [B][CHID][HW]
    const float* __restrict__ wdw,          // [CHID][9]
    const float* __restrict__ bdw,          // [CHID]
    float* __restrict__ vout_base,          // [B][CQK][HW]
    size_t hid_bstride, size_t vout_bstride)
{
    __shared__ float stgq[10 * 264];     // q channel; pixel w at col w+4
    __shared__ float stgk[10 * 264];     // k channel
    __shared__ float qk[2 * QK_CH];      // depthwise q,k

    const float* hidden = hidden_base + blockIdx.z * hid_bstride;
    float* vout         = vout_base + blockIdx.z * vout_bstride;

    const int c  = blockIdx.y;
    const int r0 = blockIdx.x * 8;
    const int tid = threadIdx.x;

    const int row = tid >> 5;
    const int seg = (tid >> 3) & 3;
    const int i   = tid & 7;
    const int gr  = r0 + row;
    const int wp0 = seg * 64 + i * 8;

    // ---- issue q,k staging loads back-to-back (all in flight together)
    float4 qreg[3], kreg[3];
    #pragma unroll
    for (int it = 0; it < 3; ++it) {
        int f4 = it * 256 + tid;
        qreg[it] = make_float4(0.f, 0.f, 0.f, 0.f);
        if (f4 < 640) {
            int lr = f4 >> 6, p4 = f4 & 63;
            int grr = r0 - 1 + lr;
            if ((unsigned)grr < H_IMG)
                qreg[it] = *reinterpret_cast<const float4*>(
                    &hidden[(size_t)c * HW + (size_t)grr * W_IMG + p4 * 4]);
        }
    }
    #pragma unroll
    for (int it = 0; it < 3; ++it) {
        int f4 = it * 256 + tid;
        kreg[it] = make_float4(0.f, 0.f, 0.f, 0.f);
        if (f4 < 640) {
            int lr = f4 >> 6, p4 = f4 & 63;
            int grr = r0 - 1 + lr;
            if ((unsigned)grr < H_IMG)
                kreg[it] = *reinterpret_cast<const float4*>(
                    &hidden[(size_t)(c + CQK) * HW + (size_t)grr * W_IMG + p4 * 4]);
        }
    }

    // ---- write both to LDS; zero halo cols (3, 260)
    #pragma unroll
    for (int it = 0; it < 3; ++it) {
        int f4 = it * 256 + tid;
        if (f4 < 640) {
            int lr = f4 >> 6, p4 = f4 & 63;
            *reinterpret_cast<float4*>(&stgq[lr * 264 + 4 + p4 * 4]) = qreg[it];
            *reinterpret_cast<float4*>(&stgk[lr * 264 + 4 + p4 * 4]) = kreg[it];
        }
    }
    if (tid < 10) {
        stgq[tid * 264 + 3]   = 0.f;
        stgq[tid * 264 + 260] = 0.f;
        stgk[tid * 264 + 3]   = 0.f;
        stgk[tid * 264 + 260] = 0.f;
    }

    // ---- issue v loads (consumed in phase 2; stay in flight across barriers)
    const float* hbv = hidden + (size_t)(c + 2 * CQK) * HW;
    float4 hv[3][2];
    float  hm[3], hp[3];
    #pragma unroll
    for (int ky = 0; ky < 3; ++ky) {
        int grr = gr + ky - 1;
        hv[ky][0] = make_float4(0.f, 0.f, 0.f, 0.f);
        hv[ky][1] = make_float4(0.f, 0.f, 0.f, 0.f);
        hm[ky] = 0.f; hp[ky] = 0.f;
        if ((unsigned)grr < H_IMG) {
            const float* rb = hbv + (size_t)grr * W_IMG;
            hv[ky][0] = *reinterpret_cast<const float4*>(&rb[wp0]);
            hv[ky][1] = *reinterpret_cast<const float4*>(&rb[wp0 + 4]);
            hm[ky] = (wp0 > 0)   ? rb[wp0 - 1] : 0.f;
            hp[ky] = (wp0 < 248) ? rb[wp0 + 8] : 0.f;
        }
    }

    __syncthreads();                     // staging complete

    const int w = tid;
    const int segw = w >> 6;
    const int tw   = w & 63;

    // ---- depthwise q then k, no intervening sync
    #pragma unroll
    for (int ch = 0; ch < 2; ++ch) {
        const float* S = ch ? stgk : stgq;
        const float* wv = wdw + (c + ch * CQK) * 9;   // block-uniform -> scalar loads
        const float bias = bdw[c + ch * CQK];
        const float w0 = wv[0], w1 = wv[1], w2 = wv[2];
        const float w3 = wv[3], w4 = wv[4], w5 = wv[5];
        const float w6 = wv[6], w7 = wv[7], w8 = wv[8];

        const float* S0 = S + w + 3;
        float am = S0[0],   a0 = S0[1],   ap = S0[2];
        float bm = S0[264], b0 = S0[265], bp = S0[266];
        #pragma unroll
        for (int r = 0; r < 8; ++r) {
            const float* Sr = S0 + (r + 2) * 264;
            float cm = Sr[0], c0 = Sr[1], cp = Sr[2];
            float a = bias + am * w0 + a0 * w1 + ap * w2
                           + bm * w3 + b0 * w4 + bp * w5
                           + cm * w6 + c0 * w7 + cp * w8;
            qk[ch * QK_CH + r * QK_ROW + segw * QK_SEG + tw] = a;
            am = bm; a0 = b0; ap = bp;
            bm = cm; b0 = c0; bp = cp;
        }
    }
    __syncthreads();

    // ---- phase 2: 8x8 circular conv + v depthwise (regs) + multiply
    const float* qb = &qk[row * QK_ROW + seg * QK_SEG];
    const float* kb = &qk[QK_CH + row * QK_ROW + seg * QK_SEG];

    float acc[8];
    #pragma unroll
    for (int j = 0; j < 8; ++j) acc[j] = 0.f;

    #pragma unroll
    for (int s = 0; s < 8; ++s) {
        int qr = (i - s) & 7;
        float4 ka = *reinterpret_cast<const float4*>(&kb[s * 8]);
        float4 kc = *reinterpret_cast<const float4*>(&kb[s * 8 + 4]);
        float4 qa = *reinterpret_cast<const float4*>(&qb[qr * 8]);
        float4 qc = *reinterpret_cast<const float4*>(&qb[qr * 8 + 4]);
        float kr[8] = {ka.x, ka.y, ka.z, ka.w, kc.x, kc.y, kc.z, kc.w};
        float qv[8] = {qa.x, qa.y, qa.z, qa.w, qc.x, qc.y, qc.z, qc.w};
        #pragma unroll
        for (int t = 0; t < 8; ++t)
            #pragma unroll
            for (int j = 0; j < 8; ++j)
                acc[j] += kr[t] * qv[(j - t) & 7];
    }

    const float* wvv = wdw + (c + 2 * CQK) * 9;
    const float vbias = bdw[c + 2 * CQK];
    float vc[8];
    #pragma unroll
    for (int j = 0; j < 8; ++j) vc[j] = vbias;
    #pragma unroll
    for (int ky = 0; ky < 3; ++ky) {
        float kw0 = wvv[ky * 3], kw1 = wvv[ky * 3 + 1], kw2 = wvv[ky * 3 + 2];
        float h[10];
        h[0] = hm[ky];
        h[1] = hv[ky][0].x; h[2] = hv[ky][0].y; h[3] = hv[ky][0].z; h[4] = hv[ky][0].w;
        h[5] = hv[ky][1].x; h[6] = hv[ky][1].y; h[7] = hv[ky][1].z; h[8] = hv[ky][1].w;
        h[9] = hp[ky];
        #pragma unroll
        for (int j = 0; j < 8; ++j)
            vc[j] += h[j] * kw0 + h[j + 1] * kw1 + h[j + 2] * kw2;
    }

    float* dst = &vout[(size_t)c * HW + (size_t)gr * W_IMG + wp0];
    float4 o0, o1;
    o0.x = acc[0] * vc[0]; o0.y = acc[1] * vc[1];
    o0.z = acc[2] * vc[2]; o0.w = acc[3] * vc[3];
    o1.x = acc[4] * vc[4]; o1.y = acc[5] * vc[5];
    o1.z = acc[6] * vc[6]; o1.w = acc[7] * vc[7];
    *reinterpret_cast<float4*>(dst)     = o0;
    *reinterpret_cast<float4*>(dst + 4) = o1;
}

extern "C" void kernel_launch(void* const* d_in, const int* in_sizes, int n_in,
                              void* d_out, int out_size, void* d_ws, size_t ws_size,
                              hipStream_t stream) {
    const float* x   = (const float*)d_in[0];
    const float* wh  = (const float*)d_in[1];
    const float* bh  = (const float*)d_in[2];
    const float* wdw = (const float*)d_in[3];
    const float* bdw = (const float*)d_in[4];
    const float* wo  = (const float*)d_in[5];
    const float* bo  = (const float*)d_in[6];
    float* out = (float*)d_out;

    const size_t n_hid  = (size_t)CHID * HW;
    const size_t n_vout = (size_t)CQK * HW;
    const size_t n_x    = (size_t)CIN * HW;

    if (ws_size >= 4 * (n_hid + n_vout) * sizeof(float)) {
        // fully batched: 3 dispatches
        float* hidden = (float*)d_ws;
        float* vout   = hidden + 4 * n_hid;
        k1_expand <<<dim3(HW / 256, CHID / 48, 4), 256, 0, stream>>>(
            x, wh, bh, hidden, n_x, n_hid);
        k2_fused  <<<dim3(H_IMG / 8, CQK, 4),      256, 0, stream>>>(
            hidden, wdw, bdw, vout, n_hid, n_vout);
        k3_project<<<dim3(HW / 256, 64 / 16, 4),   256, 0, stream>>>(
            vout, wo, bo, out, n_vout, n_x);
    } else {
        // per-batch pipeline with k3(b) + k1(b+1) merged (9 dispatches)
        float* hidden = (float*)d_ws;
        float* vout   = hidden + n_hid;
        k1_expand<<<dim3(HW / 256, CHID / 48, 1), 256, 0, stream>>>(
            x, wh, bh, hidden, 0, 0);
        for (int b = 0; b < 4; ++b) {
            k2_fused<<<dim3(H_IMG / 8, CQK, 1), 256, 0, stream>>>(
                hidden, wdw, bdw, vout, 0, 0);
            float* ob = out + (size_t)b * n_x;
            if (b < 3) {
                const float* xn = x + (size_t)(b + 1) * n_x;
                k31_merged<<<dim3(HW / 256, 12, 1), 256, 0, stream>>>(
                    xn, wh, bh, hidden, vout, wo, bo, ob);
            } else {
                k3_project<<<dim3(HW / 256, 64 / 16, 1), 256, 0, stream>>>(
                    vout, wo, bo, ob, 0, 0);
            }
        }
    }
}